// Round 6
// baseline (733.120 us; speedup 1.0000x reference)
//
#include <hip/hip_runtime.h>
#include <math.h>

#define HW 4096      // 64*64
#define CS 32        // channels per branch
#define NS 128       // B*GROUPS samples
#define NPLANES 8192 // NS * 64
#define EPS 1e-5f

__device__ __forceinline__ float sigmoidf_(float x) {
    return 1.0f / (1.0f + __expf(-x));
}

// One block per plane. Group = (sample, branch) = 32 consecutive blocks.
// x plane staged in registers; output written from registers (x read ONCE).
__global__ __launch_bounds__(256) void fused_kernel(
    const float* __restrict__ x, float* __restrict__ out,
    const float* __restrict__ cw,  const float* __restrict__ cb,
    const float* __restrict__ sw,  const float* __restrict__ sb,
    const float* __restrict__ gnw, const float* __restrict__ gnb,
    const float* __restrict__ fc1w, const float* __restrict__ fc1b,
    const float* __restrict__ lnw, const float* __restrict__ lnb,
    const float* __restrict__ fc2w, const float* __restrict__ fc2b,
    float* __restrict__ pvbuf, unsigned int* __restrict__ cnt) {
    const int P = blockIdx.x;
    const int n = P >> 6, cc = P & 63;
    const int branch = cc >> 5;          // uniform per block
    const int c = cc & 31;
    const int g = (n << 1) | branch;     // group id 0..255
    const int tid = threadIdx.x;

    __shared__ float ls[4], ls2[4];
    __shared__ float bc[4];              // 0:mu 1:rs 2:g0 3:scale

    // ---- stage 16 floats/thread, accumulate sum & sumsq ----
    const float4* xp = (const float4*)(x + (size_t)P * HW);
    float4 v[4];
    float s = 0.f, s2 = 0.f;
#pragma unroll
    for (int k = 0; k < 4; ++k) {
        v[k] = xp[tid + k * 256];
        s  += v[k].x + v[k].y + v[k].z + v[k].w;
        s2 += v[k].x * v[k].x + v[k].y * v[k].y
            + v[k].z * v[k].z + v[k].w * v[k].w;
    }
    for (int off = 32; off > 0; off >>= 1) {
        s  += __shfl_down(s, off, 64);
        s2 += __shfl_down(s2, off, 64);
    }
    const int wave = tid >> 6, lane = tid & 63;
    if (lane == 0) { ls[wave] = s; ls2[wave] = s2; }
    __syncthreads();

    if (branch == 0) {
        if (tid == 0) {
            float mean = (ls[0] + ls[1] + ls[2] + ls[3]) * (1.0f / HW);
            float g0 = sigmoidf_(cw[c] * mean + cb[c]);
            bc[2] = g0;
            float pv = mean * (1.0f - g0);   // mean of x_reid_0
            __hip_atomic_store(&pvbuf[g * CS + c], pv,
                               __ATOMIC_RELAXED, __HIP_MEMORY_SCOPE_AGENT);
            __hip_atomic_fetch_add(&cnt[g], 1u,
                                   __ATOMIC_RELEASE, __HIP_MEMORY_SCOPE_AGENT);
        }
    } else {
        if (tid == 0) {
            float mu  = (ls[0] + ls[1] + ls[2] + ls[3]) * (1.0f / HW);
            float var = (ls2[0] + ls2[1] + ls2[2] + ls2[3]) * (1.0f / HW) - mu * mu;
            bc[0] = mu;
            bc[1] = rsqrtf(var + EPS);
        }
        __syncthreads();
        const float mu = bc[0], rs = bc[1];
        const float a   = gnw[c] * rs;
        const float b0  = gnb[c] - mu * a;
        const float sbv = sb[c];
        const float4* wp = (const float4*)(sw + (size_t)c * HW);
        float sx = 0.f;
#pragma unroll
        for (int k = 0; k < 4; ++k) {
            float4 w = wp[tid + k * 256];
            sx += v[k].x * sigmoidf_(w.x * (v[k].x * a + b0) + sbv);
            sx += v[k].y * sigmoidf_(w.y * (v[k].y * a + b0) + sbv);
            sx += v[k].z * sigmoidf_(w.z * (v[k].z * a + b0) + sbv);
            sx += v[k].w * sigmoidf_(w.w * (v[k].w * a + b0) + sbv);
        }
        for (int off = 32; off > 0; off >>= 1) sx += __shfl_down(sx, off, 64);
        if (lane == 0) ls[wave] = sx;    // safe: prior ls reads done before this sync
        __syncthreads();
        if (tid == 0) {
            float sxt = ls[0] + ls[1] + ls[2] + ls[3];
            float pv = mu - sxt * (1.0f / HW);   // mean of x_reid_1
            __hip_atomic_store(&pvbuf[g * CS + c], pv,
                               __ATOMIC_RELAXED, __HIP_MEMORY_SCOPE_AGENT);
            __hip_atomic_fetch_add(&cnt[g], 1u,
                                   __ATOMIC_RELEASE, __HIP_MEMORY_SCOPE_AGENT);
        }
    }

    // ---- wait for the 31 sibling planes of this (sample, branch) ----
    if (tid == 0) {
        while (__hip_atomic_load(&cnt[g], __ATOMIC_ACQUIRE,
                                 __HIP_MEMORY_SCOPE_AGENT) < 32u)
            __builtin_amdgcn_s_sleep(2);
    }
    __syncthreads();

    // ---- redundant gate MLP on wave 0, lanes 0..31 ----
    if (tid < CS) {
        float pj = __hip_atomic_load(&pvbuf[g * CS + tid],
                                     __ATOMIC_RELAXED, __HIP_MEMORY_SCOPE_AGENT);
        float qv = fc1b[tid];
#pragma unroll 8
        for (int j = 0; j < CS; ++j) qv += fc1w[tid * CS + j] * __shfl(pj, j, 64);
        float bs = qv, bs2 = qv * qv;
        for (int m = 1; m < 32; m <<= 1) {
            bs  += __shfl_xor(bs,  m, 64);
            bs2 += __shfl_xor(bs2, m, 64);
        }
        float mu  = bs * (1.0f / CS);
        float var = bs2 * (1.0f / CS) - mu * mu;
        float qn  = (qv - mu) * rsqrtf(var + EPS) * lnw[tid] + lnb[tid];
        float r   = fmaxf(qn, 0.f);
        float sv  = fc2b[tid];
#pragma unroll 8
        for (int j = 0; j < CS; ++j) sv += fc2w[tid * CS + j] * __shfl(r, j, 64);
        float gd  = sigmoidf_(sv);
        float gdc = __shfl(gd, c, 64);   // this block's channel
        if (tid == 0) bc[3] = branch ? gdc : (bc[2] + (1.0f - bc[2]) * gdc);
    }
    __syncthreads();
    const float sc = bc[3];

    // ---- output from staged registers (no x re-read) ----
    float4* op = (float4*)(out + (size_t)P * HW);
    if (branch == 0) {
#pragma unroll
        for (int k = 0; k < 4; ++k) {
            float4 o = v[k];
            o.x *= sc; o.y *= sc; o.z *= sc; o.w *= sc;
            op[tid + k * 256] = o;
        }
    } else {
        const float mu = bc[0], rs = bc[1];
        const float a   = gnw[c] * rs;
        const float b0  = gnb[c] - mu * a;
        const float sbv = sb[c];
        const float4* wp = (const float4*)(sw + (size_t)c * HW);
#pragma unroll
        for (int k = 0; k < 4; ++k) {
            float4 w = wp[tid + k * 256];  // L2-hot (2nd stream of sw)
            float4 o; float sg;
            sg = sigmoidf_(w.x * (v[k].x * a + b0) + sbv); o.x = v[k].x * (sg + (1.f - sg) * sc);
            sg = sigmoidf_(w.y * (v[k].y * a + b0) + sbv); o.y = v[k].y * (sg + (1.f - sg) * sc);
            sg = sigmoidf_(w.z * (v[k].z * a + b0) + sbv); o.z = v[k].z * (sg + (1.f - sg) * sc);
            sg = sigmoidf_(w.w * (v[k].w * a + b0) + sbv); o.w = v[k].w * (sg + (1.f - sg) * sc);
            op[tid + k * 256] = o;
        }
    }
}

extern "C" void kernel_launch(void* const* d_in, const int* in_sizes, int n_in,
                              void* d_out, int out_size, void* d_ws, size_t ws_size,
                              hipStream_t stream) {
    const float* x    = (const float*)d_in[0];
    const float* cw   = (const float*)d_in[1];
    const float* cb   = (const float*)d_in[2];
    const float* sw   = (const float*)d_in[3];
    const float* sb   = (const float*)d_in[4];
    const float* gnw  = (const float*)d_in[5];
    const float* gnb  = (const float*)d_in[6];
    const float* fc1w = (const float*)d_in[7];
    const float* fc1b = (const float*)d_in[8];
    const float* lnw  = (const float*)d_in[9];
    const float* lnb  = (const float*)d_in[10];
    const float* fc2w = (const float*)d_in[11];
    const float* fc2b = (const float*)d_in[12];
    float* out = (float*)d_out;

    unsigned int* cnt = (unsigned int*)d_ws;          // 256 counters (1 KB)
    float* pvbuf      = (float*)((char*)d_ws + 1024); // 8192 floats

    hipMemsetAsync(cnt, 0, 1024, stream);             // re-zero every call (capturable)
    fused_kernel<<<NPLANES, 256, 0, stream>>>(x, out, cw, cb, sw, sb,
                                              gnw, gnb, fc1w, fc1b,
                                              lnw, lnb, fc2w, fc2b,
                                              pvbuf, cnt);
}

// Round 8
// 166.389 us; speedup vs baseline: 4.4061x; 4.4061x over previous
//
#include <hip/hip_runtime.h>
#include <math.h>

#define HW 4096      // 64*64
#define CS 32        // channels per branch
#define NS 128       // B*GROUPS samples
#define NBLK 1024    // 4 blocks/CU * 256 CUs: all resident by construction
#define EPS 1e-5f

__device__ __forceinline__ float sigmoidf_(float x) {
    return 1.0f / (1.0f + __expf(-x));
}

// Persistent-resident fused kernel. block b: sample n=b>>3, slice s=b&7 ->
// channels c=4s..4s+3 of each branch. Branch1 planes staged in registers
// (64 VGPR), branch0 planes streamed then re-read post-barrier (L3-hot).
// Grid barrier: global counter, release-add + relaxed-poll + one acquire.
__global__ __launch_bounds__(256, 4) void fused_persist(
    const float* __restrict__ x, float* __restrict__ out,
    const float* __restrict__ cw,  const float* __restrict__ cb,
    const float* __restrict__ sw,  const float* __restrict__ sb,
    const float* __restrict__ gnw, const float* __restrict__ gnb,
    const float* __restrict__ fc1w, const float* __restrict__ fc1b,
    const float* __restrict__ lnw, const float* __restrict__ lnb,
    const float* __restrict__ fc2w, const float* __restrict__ fc2b,
    float* __restrict__ pvbuf, unsigned int* __restrict__ cnt) {
    const int b = blockIdx.x;
    const int n = b >> 3, s = b & 7;
    const int tid = threadIdx.x;
    const int wave = tid >> 6, lane = tid & 63;

    __shared__ float ls[4], ls2[4];
    __shared__ float muL[4], rsL[4], g0L[4], scL[8];

    const size_t sample4 = (size_t)n * 64 * 1024;  // float4 units
    const float4* xb = (const float4*)x;
    float4*       ob = (float4*)out;

    // ---------- phase A: branch0 plane sums (streamed) ----------
    for (int q = 0; q < 4; ++q) {
        const int c = s * 4 + q;
        const float4* xp = xb + sample4 + (size_t)c * 1024;
        float sm = 0.f;
#pragma unroll
        for (int k = 0; k < 4; ++k) {
            float4 vv = xp[tid + k * 256];
            sm += vv.x + vv.y + vv.z + vv.w;
        }
        for (int off = 32; off; off >>= 1) sm += __shfl_down(sm, off, 64);
        if (lane == 0) ls[wave] = sm;
        __syncthreads();
        if (tid == 0) {
            float mean = (ls[0] + ls[1] + ls[2] + ls[3]) * (1.0f / HW);
            float g0 = sigmoidf_(cw[c] * mean + cb[c]);
            g0L[q] = g0;
            pvbuf[n * 64 + c] = mean * (1.0f - g0);   // mean of x_reid_0
        }
        __syncthreads();
    }

    // ---------- phase B: branch1 planes, staged in registers ----------
    float4 v[4][4];
    for (int q = 0; q < 4; ++q) {
        const int c = s * 4 + q;
        const float4* xp = xb + sample4 + (size_t)(CS + c) * 1024;
        float sm = 0.f, s2 = 0.f;
#pragma unroll
        for (int k = 0; k < 4; ++k) {
            v[q][k] = xp[tid + k * 256];
            sm += v[q][k].x + v[q][k].y + v[q][k].z + v[q][k].w;
            s2 += v[q][k].x * v[q][k].x + v[q][k].y * v[q][k].y
                + v[q][k].z * v[q][k].z + v[q][k].w * v[q][k].w;
        }
        for (int off = 32; off; off >>= 1) {
            sm += __shfl_down(sm, off, 64);
            s2 += __shfl_down(s2, off, 64);
        }
        if (lane == 0) { ls[wave] = sm; ls2[wave] = s2; }
        __syncthreads();
        if (tid == 0) {
            float mu  = (ls[0] + ls[1] + ls[2] + ls[3]) * (1.0f / HW);
            float var = (ls2[0] + ls2[1] + ls2[2] + ls2[3]) * (1.0f / HW) - mu * mu;
            muL[q] = mu;
            rsL[q] = rsqrtf(var + EPS);
        }
        __syncthreads();
        const float mu = muL[q], rs = rsL[q];
        const float a   = gnw[c] * rs;
        const float b0  = gnb[c] - mu * a;
        const float sbv = sb[c];
        const float4* wp = (const float4*)sw + (size_t)c * 1024;
        float sx = 0.f;
#pragma unroll
        for (int k = 0; k < 4; ++k) {
            float4 w = wp[tid + k * 256];
            sx += v[q][k].x * sigmoidf_(w.x * (v[q][k].x * a + b0) + sbv);
            sx += v[q][k].y * sigmoidf_(w.y * (v[q][k].y * a + b0) + sbv);
            sx += v[q][k].z * sigmoidf_(w.z * (v[q][k].z * a + b0) + sbv);
            sx += v[q][k].w * sigmoidf_(w.w * (v[q][k].w * a + b0) + sbv);
        }
        for (int off = 32; off; off >>= 1) sx += __shfl_down(sx, off, 64);
        if (lane == 0) ls[wave] = sx;
        __syncthreads();
        if (tid == 0)
            pvbuf[n * 64 + CS + c] = muL[q] - (ls[0] + ls[1] + ls[2] + ls[3]) * (1.0f / HW);
        __syncthreads();
    }

    // ---------- grid barrier (all 1024 blocks resident -> no deadlock) ----------
    if (tid == 0) {
        // release: writes back this thread's pvbuf stores to coherence point
        __hip_atomic_fetch_add(cnt, 1u, __ATOMIC_ACQ_REL, __HIP_MEMORY_SCOPE_AGENT);
        int spins = 0;
        while (__hip_atomic_load(cnt, __ATOMIC_RELAXED, __HIP_MEMORY_SCOPE_AGENT)
                   < (unsigned)NBLK
               && ++spins < (1 << 19))
            __builtin_amdgcn_s_sleep(8);
        // single acquire: invalidate stale L1/L2 so pvbuf reads below are fresh
        (void)__hip_atomic_load(cnt, __ATOMIC_ACQUIRE, __HIP_MEMORY_SCOPE_AGENT);
    }
    __syncthreads();

    // ---------- phase C: both gate MLPs for sample n (wave 0) ----------
    if (wave == 0) {
        const int c = lane & 31;             // channel; lane>>5 = branch
        float pv = pvbuf[n * 64 + lane];
        float qv = fc1b[c];
#pragma unroll 8
        for (int j = 0; j < CS; ++j)
            qv += fc1w[c * CS + j] * __shfl(pv, (lane & 32) + j, 64);
        float bs = qv, bs2 = qv * qv;
        for (int m = 1; m < 32; m <<= 1) {   // stays within each 32-lane half
            bs  += __shfl_xor(bs,  m, 64);
            bs2 += __shfl_xor(bs2, m, 64);
        }
        float mu  = bs * (1.0f / CS);
        float var = bs2 * (1.0f / CS) - mu * mu;
        float r   = fmaxf((qv - mu) * rsqrtf(var + EPS) * lnw[c] + lnb[c], 0.f);
        float sv  = fc2b[c];
#pragma unroll 8
        for (int j = 0; j < CS; ++j)
            sv += fc2w[c * CS + j] * __shfl(r, (lane & 32) + j, 64);
        float gd = sigmoidf_(sv);
        if ((c >> 2) == s) {                 // one of this block's 4 channels
            const int q = c & 3;
            if (lane < 32) scL[q]     = g0L[q] + (1.0f - g0L[q]) * gd;
            else           scL[4 + q] = gd;
        }
    }
    __syncthreads();

    // ---------- phase D1: branch1 outputs from staged registers ----------
    for (int q = 0; q < 4; ++q) {
        const int c = s * 4 + q;
        const float a   = gnw[c] * rsL[q];
        const float b0  = gnb[c] - muL[q] * a;
        const float sbv = sb[c];
        const float g   = scL[4 + q];
        const float4* wp = (const float4*)sw + (size_t)c * 1024;
        float4* op = ob + sample4 + (size_t)(CS + c) * 1024;
#pragma unroll
        for (int k = 0; k < 4; ++k) {
            float4 w = wp[tid + k * 256];   // repeat stream of sw: cache-hot
            float4 o; float sg;
            sg = sigmoidf_(w.x * (v[q][k].x * a + b0) + sbv); o.x = v[q][k].x * (sg + (1.f - sg) * g);
            sg = sigmoidf_(w.y * (v[q][k].y * a + b0) + sbv); o.y = v[q][k].y * (sg + (1.f - sg) * g);
            sg = sigmoidf_(w.z * (v[q][k].z * a + b0) + sbv); o.z = v[q][k].z * (sg + (1.f - sg) * g);
            sg = sigmoidf_(w.w * (v[q][k].w * a + b0) + sbv); o.w = v[q][k].w * (sg + (1.f - sg) * g);
            op[tid + k * 256] = o;
        }
    }

    // ---------- phase D2: branch0 outputs (re-read, expected L3-hot) ----------
    for (int q = 0; q < 4; ++q) {
        const int c = s * 4 + q;
        const float sc = scL[q];
        const float4* xp = xb + sample4 + (size_t)c * 1024;
        float4* op = ob + sample4 + (size_t)c * 1024;
#pragma unroll
        for (int k = 0; k < 4; ++k) {
            float4 o = xp[tid + k * 256];
            o.x *= sc; o.y *= sc; o.z *= sc; o.w *= sc;
            op[tid + k * 256] = o;
        }
    }
}

extern "C" void kernel_launch(void* const* d_in, const int* in_sizes, int n_in,
                              void* d_out, int out_size, void* d_ws, size_t ws_size,
                              hipStream_t stream) {
    const float* x    = (const float*)d_in[0];
    const float* cw   = (const float*)d_in[1];
    const float* cb   = (const float*)d_in[2];
    const float* sw   = (const float*)d_in[3];
    const float* sb   = (const float*)d_in[4];
    const float* gnw  = (const float*)d_in[5];
    const float* gnb  = (const float*)d_in[6];
    const float* fc1w = (const float*)d_in[7];
    const float* fc1b = (const float*)d_in[8];
    const float* lnw  = (const float*)d_in[9];
    const float* lnb  = (const float*)d_in[10];
    const float* fc2w = (const float*)d_in[11];
    const float* fc2b = (const float*)d_in[12];
    float* out = (float*)d_out;

    unsigned int* cnt = (unsigned int*)d_ws;          // 1 counter
    float* pvbuf      = (float*)((char*)d_ws + 256);  // 8192 floats

    hipMemsetAsync(cnt, 0, 256, stream);              // re-zero every call
    fused_persist<<<NBLK, 256, 0, stream>>>(x, out, cw, cb, sw, sb,
                                            gnw, gnb, fc1w, fc1b,
                                            lnw, lnb, fc2w, fc2b,
                                            pvbuf, cnt);
}

// Round 9
// 67.637 us; speedup vs baseline: 10.8390x; 2.4600x over previous
//
#include <hip/hip_runtime.h>
#include <math.h>

#define HW 4096      // 64*64
#define CS 32        // channels per branch
#define NS 128       // B*GROUPS samples
#define NPLANES 8192 // NS * 64
#define EPS 1e-5f

typedef float vfloat4 __attribute__((ext_vector_type(4)));

__device__ __forceinline__ float sigmoidf_(float x) {
    return 1.0f / (1.0f + __expf(-x));
}

__device__ __forceinline__ void nt_store4(float4* p, float4 v) {
    __builtin_nontemporal_store(*(const vfloat4*)&v, (vfloat4*)p);
}

// block-wide (256 thr, 4 waves) sum reduce; result valid in all threads
__device__ __forceinline__ float block_reduce(float s, float* ls, int tid) {
    for (int off = 32; off > 0; off >>= 1) s += __shfl_down(s, off, 64);
    const int wave = tid >> 6, lane = tid & 63;
    if (lane == 0) ls[wave] = s;
    __syncthreads();
    return ls[0] + ls[1] + ls[2] + ls[3];
}

// ---------------- K1: one read of x.
// branch0 plane -> channel sum; branch1 plane -> mu, rs, sum(xs) (reg-staged)
__global__ __launch_bounds__(256) void pass1_kernel(
    const float* __restrict__ x,
    const float* __restrict__ gnw, const float* __restrict__ gnb,
    const float* __restrict__ sw,  const float* __restrict__ sb,
    float* __restrict__ sums0, float* __restrict__ mu1,
    float* __restrict__ rs1,   float* __restrict__ sumxs) {
    const int P = blockIdx.x;
    const int n = P >> 6, cc = P & 63;
    const int tid = threadIdx.x;
    const float4* xp = (const float4*)(x + (size_t)P * HW);
    __shared__ float ls[4];
    __shared__ float bc[2];

    if (cc < CS) {
        float s = 0.f;
#pragma unroll
        for (int k = 0; k < 4; ++k) {
            float4 v = xp[tid + k * 256];
            s += v.x + v.y + v.z + v.w;
        }
        s = block_reduce(s, ls, tid);
        if (tid == 0) sums0[n * CS + cc] = s;
    } else {
        const int c = cc - CS;
        float4 v[4];
        float s = 0.f, s2 = 0.f;
#pragma unroll
        for (int k = 0; k < 4; ++k) {
            v[k] = xp[tid + k * 256];
            s  += v[k].x + v[k].y + v[k].z + v[k].w;
            s2 += v[k].x * v[k].x + v[k].y * v[k].y
                + v[k].z * v[k].z + v[k].w * v[k].w;
        }
        for (int off = 32; off > 0; off >>= 1) {
            s  += __shfl_down(s, off, 64);
            s2 += __shfl_down(s2, off, 64);
        }
        __shared__ float ls2[4];
        const int wave = tid >> 6, lane = tid & 63;
        if (lane == 0) { ls[wave] = s; ls2[wave] = s2; }
        __syncthreads();
        if (tid == 0) {
            float st  = ls[0] + ls[1] + ls[2] + ls[3];
            float s2t = ls2[0] + ls2[1] + ls2[2] + ls2[3];
            float mu  = st * (1.0f / HW);
            float var = s2t * (1.0f / HW) - mu * mu;
            float rs  = rsqrtf(var + EPS);
            mu1[n * CS + c] = mu;
            rs1[n * CS + c] = rs;
            bc[0] = mu; bc[1] = rs;
        }
        __syncthreads();
        const float mu = bc[0], rs = bc[1];
        const float a  = gnw[c] * rs;
        const float b0 = gnb[c] - mu * a;
        const float sbv = sb[c];
        const float4* wp = (const float4*)(sw + (size_t)c * HW);
        float sx = 0.f;
#pragma unroll
        for (int k = 0; k < 4; ++k) {
            float4 w = wp[tid + k * 256];
            sx += v[k].x * sigmoidf_(w.x * (v[k].x * a + b0) + sbv);
            sx += v[k].y * sigmoidf_(w.y * (v[k].y * a + b0) + sbv);
            sx += v[k].z * sigmoidf_(w.z * (v[k].z * a + b0) + sbv);
            sx += v[k].w * sigmoidf_(w.w * (v[k].w * a + b0) + sbv);
        }
        __syncthreads();   // ls reuse
        sx = block_reduce(sx, ls, tid);
        if (tid == 0) sumxs[n * CS + c] = sx;
    }
}

// ---------------- K2: fused gates + output pass (both branches)
// REVERSE plane order: blocks start on the planes pass1 touched last (L3-hot)
__global__ __launch_bounds__(256) void out_kernel(
    const float* __restrict__ x, float* __restrict__ out,
    const float* __restrict__ sums0,
    const float* __restrict__ mu1, const float* __restrict__ rs1,
    const float* __restrict__ sumxs,
    const float* __restrict__ cw,  const float* __restrict__ cb,
    const float* __restrict__ gnw, const float* __restrict__ gnb,
    const float* __restrict__ sw,  const float* __restrict__ sb,
    const float* __restrict__ fc1w, const float* __restrict__ fc1b,
    const float* __restrict__ lnw, const float* __restrict__ lnb,
    const float* __restrict__ fc2w, const float* __restrict__ fc2b) {
    const int P = (NPLANES - 1) - blockIdx.x;   // reverse order
    const int n = P >> 6, cc = P & 63;
    const int tid = threadIdx.x;
    const int branch = (cc >= CS);
    const int c0 = cc & 31;

    __shared__ float pS[CS], qS[CS], rS[CS], g0S[CS];
    __shared__ float scaleS;

    // ---- redundant per-block gate MLP (threads of wave 0) ----
    if (tid < CS) {
        float pv;
        if (!branch) {
            float mean = sums0[n * CS + tid] * (1.0f / HW);
            float g0 = sigmoidf_(cw[tid] * mean + cb[tid]);
            g0S[tid] = g0;
            pv = mean * (1.0f - g0);          // mean of x_reid_0
        } else {
            pv = mu1[n * CS + tid] - sumxs[n * CS + tid] * (1.0f / HW);
        }
        pS[tid] = pv;
    }
    __syncthreads();
    if (tid < CS) {
        float qv = fc1b[tid];
        for (int j = 0; j < CS; ++j) qv += fc1w[tid * CS + j] * pS[j];
        qS[tid] = qv;
    }
    __syncthreads();
    if (tid < CS) {
        float mu = 0.f;
        for (int j = 0; j < CS; ++j) mu += qS[j];
        mu *= (1.0f / CS);
        float var = 0.f;
        for (int j = 0; j < CS; ++j) { float d = qS[j] - mu; var += d * d; }
        var *= (1.0f / CS);
        float qn = (qS[tid] - mu) * rsqrtf(var + EPS) * lnw[tid] + lnb[tid];
        rS[tid] = fmaxf(qn, 0.f);
    }
    __syncthreads();
    if (tid < 64) {   // whole wave 0 active -> well-defined shuffles
        float t = (tid < CS) ? fc2w[c0 * CS + tid] * rS[tid] : 0.f;
        for (int off = 32; off > 0; off >>= 1) t += __shfl_down(t, off, 64);
        if (tid == 0) {
            float gd = sigmoidf_(t + fc2b[c0]);
            scaleS = branch ? gd : (g0S[c0] + (1.0f - g0S[c0]) * gd);
        }
    }
    __syncthreads();

    const float4* xp = (const float4*)(x + (size_t)P * HW);
    float4* op = (float4*)(out + (size_t)P * HW);

    if (!branch) {
        const float scale = scaleS;
#pragma unroll
        for (int k = 0; k < 4; ++k) {
            float4 v = xp[tid + k * 256];
            v.x *= scale; v.y *= scale; v.z *= scale; v.w *= scale;
            nt_store4(op + tid + k * 256, v);   // nt: don't evict x from L3
        }
    } else {
        const float g  = scaleS;
        const float mu = mu1[n * CS + c0], rs = rs1[n * CS + c0];
        const float a  = gnw[c0] * rs;
        const float b0 = gnb[c0] - mu * a;
        const float sbv = sb[c0];
        const float4* wp = (const float4*)(sw + (size_t)c0 * HW);
#pragma unroll
        for (int k = 0; k < 4; ++k) {
            float4 v = xp[tid + k * 256];
            float4 w = wp[tid + k * 256];
            float4 o; float sg;
            sg = sigmoidf_(w.x * (v.x * a + b0) + sbv); o.x = v.x * (sg + (1.f - sg) * g);
            sg = sigmoidf_(w.y * (v.y * a + b0) + sbv); o.y = v.y * (sg + (1.f - sg) * g);
            sg = sigmoidf_(w.z * (v.z * a + b0) + sbv); o.z = v.z * (sg + (1.f - sg) * g);
            sg = sigmoidf_(w.w * (v.w * a + b0) + sbv); o.w = v.w * (sg + (1.f - sg) * g);
            nt_store4(op + tid + k * 256, o);
        }
    }
}

extern "C" void kernel_launch(void* const* d_in, const int* in_sizes, int n_in,
                              void* d_out, int out_size, void* d_ws, size_t ws_size,
                              hipStream_t stream) {
    const float* x    = (const float*)d_in[0];
    const float* cw   = (const float*)d_in[1];
    const float* cb   = (const float*)d_in[2];
    const float* sw   = (const float*)d_in[3];
    const float* sb   = (const float*)d_in[4];
    const float* gnw  = (const float*)d_in[5];
    const float* gnb  = (const float*)d_in[6];
    const float* fc1w = (const float*)d_in[7];
    const float* fc1b = (const float*)d_in[8];
    const float* lnw  = (const float*)d_in[9];
    const float* lnb  = (const float*)d_in[10];
    const float* fc2w = (const float*)d_in[11];
    const float* fc2b = (const float*)d_in[12];
    float* out = (float*)d_out;
    float* ws  = (float*)d_ws;

    float* sums0 = ws;             // 4096
    float* mu1   = ws + 4096;      // 4096
    float* rs1   = ws + 8192;      // 4096
    float* sumxs = ws + 12288;     // 4096

    pass1_kernel<<<NPLANES, 256, 0, stream>>>(x, gnw, gnb, sw, sb,
                                              sums0, mu1, rs1, sumxs);
    out_kernel<<<NPLANES, 256, 0, stream>>>(x, out, sums0, mu1, rs1, sumxs,
                                            cw, cb, gnw, gnb, sw, sb,
                                            fc1w, fc1b, lnw, lnb, fc2w, fc2b);
}